// Round 1
// baseline (375.122 us; speedup 1.0000x reference)
//
#include <hip/hip_runtime.h>

#define TS   32                 // output tile side
#define HALO 5                  // K/2
#define IN   (TS + 2*HALO)      // 42 input tile side
#define KSZ  11
#define IMG  512

__global__ __launch_bounds__(256)
void dssim_fused_kernel(const float* __restrict__ x,
                        const float* __restrict__ y,
                        const float* __restrict__ kern,
                        float* __restrict__ out)
{
    __shared__ float sg[KSZ];
    __shared__ float sx [IN][IN + 1];
    __shared__ float sy [IN][IN + 1];
    __shared__ float hx [IN][TS + 1];
    __shared__ float hy [IN][TS + 1];
    __shared__ float hxx[IN][TS + 1];
    __shared__ float hyy[IN][TS + 1];
    __shared__ float hxy[IN][TS + 1];

    const int tid = threadIdx.x;

    // Recover the separable 1D gaussian: row-sums of the 2D kernel
    // (k2d[i][j] = g[i]*g[j], sum_j = g[i] since sum(g) == 1).
    if (tid < KSZ) {
        float s = 0.f;
        #pragma unroll
        for (int j = 0; j < KSZ; ++j) s += kern[tid * KSZ + j];
        sg[tid] = s;
    }

    const int plane = blockIdx.z;                  // n*C + c
    const long base = (long)plane * IMG * IMG;
    const int row0 = blockIdx.y * TS;
    const int col0 = blockIdx.x * TS;

    // Stage x,y halo tile (zero padding == SAME conv padding)
    for (int idx = tid; idx < IN * IN; idx += 256) {
        const int r = idx / IN, c = idx % IN;
        const int gr = row0 + r - HALO;
        const int gc = col0 + c - HALO;
        float xv = 0.f, yv = 0.f;
        if (gr >= 0 && gr < IMG && gc >= 0 && gc < IMG) {
            const long off = base + (long)gr * IMG + gc;
            xv = x[off];
            yv = y[off];
        }
        sx[r][c] = xv;
        sy[r][c] = yv;
    }
    __syncthreads();

    // Horizontal 11-tap pass for the 5 fields
    for (int idx = tid; idx < IN * TS; idx += 256) {
        const int r = idx / TS, c = idx % TS;
        float ax = 0.f, ay = 0.f, axx = 0.f, ayy = 0.f, axy = 0.f;
        #pragma unroll
        for (int k = 0; k < KSZ; ++k) {
            const float g  = sg[k];
            const float xv = sx[r][c + k];
            const float yv = sy[r][c + k];
            ax  += g * xv;
            ay  += g * yv;
            axx += g * xv * xv;
            ayy += g * yv * yv;
            axy += g * xv * yv;
        }
        hx [r][c] = ax;
        hy [r][c] = ay;
        hxx[r][c] = axx;
        hyy[r][c] = ayy;
        hxy[r][c] = axy;
    }
    __syncthreads();

    // Vertical 11-tap pass + SSIM, 4 pixels per thread
    const float C1 = 1e-4f;        // 0.01^2
    const float C2 = 9e-4f;        // 0.03^2
    float local = 0.f;
    #pragma unroll
    for (int i = 0; i < (TS * TS) / 256; ++i) {
        const int p = tid + i * 256;
        const int r = p / TS, c = p % TS;
        float mx = 0.f, my = 0.f, exx = 0.f, eyy = 0.f, exy = 0.f;
        #pragma unroll
        for (int k = 0; k < KSZ; ++k) {
            const float g = sg[k];
            mx  += g * hx [r + k][c];
            my  += g * hy [r + k][c];
            exx += g * hxx[r + k][c];
            eyy += g * hyy[r + k][c];
            exy += g * hxy[r + k][c];
        }
        const float sxv = exx - mx * mx;
        const float syv = eyy - my * my;
        const float sxy = exy - mx * my;
        const float num = (2.f * mx * my + C1) * (2.f * sxy + C2);
        const float den = (mx * mx + my * my + C1) * (sxv + syv + C2);
        const float ssim = num / (den + 1e-8f);
        local += (1.f - ssim) * 0.5f;
    }

    // Block reduction: wave shuffle (64-wide) then LDS across 4 waves
    #pragma unroll
    for (int o = 32; o > 0; o >>= 1) local += __shfl_down(local, o, 64);
    __shared__ float wsum[4];
    if ((tid & 63) == 0) wsum[tid >> 6] = local;
    __syncthreads();
    if (tid == 0) {
        const float s = wsum[0] + wsum[1] + wsum[2] + wsum[3];
        atomicAdd(out, s * (1.f / 25165824.f));   // / (32*3*512*512)
    }
}

extern "C" void kernel_launch(void* const* d_in, const int* in_sizes, int n_in,
                              void* d_out, int out_size, void* d_ws, size_t ws_size,
                              hipStream_t stream)
{
    const float* x    = (const float*)d_in[0];
    const float* y    = (const float*)d_in[1];
    const float* kern = (const float*)d_in[2];
    float* out = (float*)d_out;

    hipMemsetAsync(out, 0, sizeof(float), stream);

    dim3 grid(IMG / TS, IMG / TS, 32 * 3);
    dssim_fused_kernel<<<grid, 256, 0, stream>>>(x, y, kern, out);
}

// Round 2
// 247.540 us; speedup vs baseline: 1.5154x; 1.5154x over previous
//
#include <hip/hip_runtime.h>

#define IMG   512
#define KSZ   11
#define HALO  5
#define BW    256                  // strip width = blockDim.x
#define BH    128                  // output rows per block
#define INW   (BW + 2*HALO)        // 266 staged columns
#define ROWS  (BH + 2*HALO)        // 138 input rows walked
#define CHUNK 11                   // rows staged per sync == ring depth

__global__ __launch_bounds__(256)
void dssim_strip_kernel(const float* __restrict__ x,
                        const float* __restrict__ y,
                        const float* __restrict__ kern,
                        float* __restrict__ out)
{
    __shared__ float sg[KSZ];
    __shared__ float sx[CHUNK][INW + 2];   // 11 x 268 floats
    __shared__ float sy[CHUNK][INW + 2];

    const int tid = threadIdx.x;

    // Recover separable 1D gaussian: row sums of 2D kernel (rows sum to g
    // since sum(g)==1). Channel 0 of the tiled depthwise kernel.
    if (tid < KSZ) {
        float s = 0.f;
        #pragma unroll
        for (int j = 0; j < KSZ; ++j) s += kern[tid * KSZ + j];
        sg[tid] = s;
    }
    __syncthreads();

    // Taps in registers — removes 22 LDS broadcast reads per pixel.
    float gk[KSZ];
    #pragma unroll
    for (int k = 0; k < KSZ; ++k) gk[k] = sg[k];

    const int plane = blockIdx.z;                   // n*C + c
    const long base = (long)plane * IMG * IMG;
    const int col0  = blockIdx.x * BW;
    const int row0  = blockIdx.y * BH;
    const int mycol = col0 + tid;                   // this thread's output column

    // Register ring buffer: 11 rows x 5 horizontally-blurred fields.
    // All indices below are compile-time constants (full unroll) so this
    // stays in VGPRs.
    float ring[CHUNK][5];

    const float C1 = 1e-4f;    // 0.01^2
    const float C2 = 9e-4f;    // 0.03^2
    float local = 0.f;

    for (int ii = 0; ii < ROWS; ii += CHUNK) {
        // ---- stage up to 11 input rows (x and y) into LDS ----
        const int nrows = min(CHUNK, ROWS - ii);
        for (int idx = tid; idx < nrows * INW; idx += BW) {
            const int j  = idx / INW;
            const int c  = idx - j * INW;
            const int gr = row0 - HALO + ii + j;
            const int gc = col0 - HALO + c;
            float xv = 0.f, yv = 0.f;
            if (gr >= 0 && gr < IMG && gc >= 0 && gc < IMG) {
                const long off = base + (long)gr * IMG + gc;
                xv = x[off];
                yv = y[off];
            }
            sx[j][c] = xv;
            sy[j][c] = yv;
        }
        __syncthreads();

        // ---- process the staged rows ----
        #pragma unroll
        for (int j = 0; j < CHUNK; ++j) {
            const int i = ii + j;                  // input-row index (uniform)
            if (i < ROWS) {
                // horizontal 11-tap blur at column mycol (LDS col tid..tid+10)
                float ax = 0.f, ay = 0.f, axx = 0.f, ayy = 0.f, axy = 0.f;
                #pragma unroll
                for (int k = 0; k < KSZ; ++k) {
                    const float g  = gk[k];
                    const float xv = sx[j][tid + k];
                    const float yv = sy[j][tid + k];
                    ax  += g * xv;
                    ay  += g * yv;
                    axx += g * xv * xv;
                    ayy += g * yv * yv;
                    axy += g * xv * yv;
                }
                ring[j][0] = ax;  ring[j][1] = ay;
                ring[j][2] = axx; ring[j][3] = ayy; ring[j][4] = axy;

                // vertical 11-tap over the ring (registers only)
                if (i >= 2 * HALO) {
                    float mx = 0.f, my = 0.f, exx = 0.f, eyy = 0.f, exy = 0.f;
                    #pragma unroll
                    for (int k = 0; k < KSZ; ++k) {
                        const int s = (j + 1 + k) % CHUNK;   // static
                        const float g = gk[k];
                        mx  += g * ring[s][0];
                        my  += g * ring[s][1];
                        exx += g * ring[s][2];
                        eyy += g * ring[s][3];
                        exy += g * ring[s][4];
                    }
                    const float sxv = exx - mx * mx;
                    const float syv = eyy - my * my;
                    const float sxy = exy - mx * my;
                    const float num = (2.f * mx * my + C1) * (2.f * sxy + C2);
                    const float den = (mx * mx + my * my + C1) * (sxv + syv + C2);
                    const float ssim = __fdividef(num, den + 1e-8f);
                    // guard: mycol always < IMG here (512 = 2*256), rows exact
                    local += (1.f - ssim) * 0.5f;
                }
            }
        }
        __syncthreads();   // WAR: ring done reading LDS before next stage
    }

    // ---- block reduction, one atomic per block ----
    #pragma unroll
    for (int o = 32; o > 0; o >>= 1) local += __shfl_down(local, o, 64);
    __shared__ float wsum[4];
    if ((tid & 63) == 0) wsum[tid >> 6] = local;
    __syncthreads();
    if (tid == 0) {
        const float s = wsum[0] + wsum[1] + wsum[2] + wsum[3];
        atomicAdd(out, s * (1.f / 25165824.f));   // / (32*3*512*512)
    }
}

extern "C" void kernel_launch(void* const* d_in, const int* in_sizes, int n_in,
                              void* d_out, int out_size, void* d_ws, size_t ws_size,
                              hipStream_t stream)
{
    const float* x    = (const float*)d_in[0];
    const float* y    = (const float*)d_in[1];
    const float* kern = (const float*)d_in[2];
    float* out = (float*)d_out;

    hipMemsetAsync(out, 0, sizeof(float), stream);

    dim3 grid(IMG / BW, IMG / BH, 32 * 3);   // 2 x 4 x 96 = 768 blocks
    dssim_strip_kernel<<<grid, BW, 0, stream>>>(x, y, kern, out);
}